// Round 9
// baseline (11308.596 us; speedup 1.0000x reference)
//
#include <hip/hip_runtime.h>
#include <hip/hip_bf16.h>

typedef unsigned short u16;
typedef unsigned int   u32;
typedef unsigned long long u64;
typedef __attribute__((ext_vector_type(8))) __bf16 bf16x8;
typedef __attribute__((ext_vector_type(4))) float   f32x4;

// async global->LDS, 16B per lane; LDS dest = wave-uniform base + lane*16
#define GLOAD16(gp, lp) __builtin_amdgcn_global_load_lds( \
    (__attribute__((address_space(1))) void*)(gp),        \
    (__attribute__((address_space(3))) void*)(lp), 16, 0, 0)

static __device__ __forceinline__ u16 f2bf(float f) {
  __bf16 b = (__bf16)f;                 // RNE convert
  return __builtin_bit_cast(u16, b);
}
static __device__ __forceinline__ f32x4 mfma16(bf16x8 a, bf16x8 b, f32x4 c) {
  return __builtin_amdgcn_mfma_f32_16x16x32_bf16(a, b, c, 0, 0, 0);
}

// ---------------- prep kernels ----------------

__global__ __launch_bounds__(256) void k_cvt_emb(const float* __restrict__ s,
                                                 u16* __restrict__ d) {
  int i = (blockIdx.x * 256 + threadIdx.x) * 4;
  float4 v = *(const float4*)(s + i);
  d[i] = f2bf(v.x); d[i+1] = f2bf(v.y); d[i+2] = f2bf(v.z); d[i+3] = f2bf(v.w);
}

__global__ __launch_bounds__(256) void k_tr_wh(const float* __restrict__ Wh,
                                               u16* __restrict__ WhxT,
                                               u16* __restrict__ WhhT) {
  __shared__ float tile[32][33];
  int bx = blockIdx.x & 31;
  int be = blockIdx.x >> 5;
  int tx = threadIdx.x & 31, ty = threadIdx.x >> 5;
  #pragma unroll
  for (int s = 0; s < 32; s += 8)
    tile[ty + s][tx] = Wh[(size_t)(be*32 + ty + s) * 1024 + bx*32 + tx];
  __syncthreads();
  #pragma unroll
  for (int s = 0; s < 32; s += 8) {
    int e = be*32 + tx;
    int j = bx*32 + ty + s;
    u16 v = f2bf(tile[tx][ty + s]);
    if (e < 512) WhxT[(size_t)j * 512 + e] = v;
    else         WhhT[(size_t)j * 1024 + (e - 512)] = v;
  }
}

__global__ __launch_bounds__(256) void k_tr_wo(const float* __restrict__ Wo,
                                               u16* __restrict__ WoT) {
  __shared__ float tile[32][33];
  int bx = blockIdx.x & 255;
  int by = blockIdx.x >> 8;
  int tx = threadIdx.x & 31, ty = threadIdx.x >> 5;
  #pragma unroll
  for (int s = 0; s < 32; s += 8)
    tile[ty + s][tx] = Wo[(size_t)(by*32 + ty + s) * 8192 + bx*32 + tx];
  __syncthreads();
  #pragma unroll
  for (int s = 0; s < 32; s += 8)
    WoT[(size_t)(bx*32 + ty + s) * 1024 + by*32 + tx] = f2bf(tile[tx][ty + s]);
}

// h0 -> ring slot 0; zero 16KB flag region (2 jobs x 16 flags, 128B apart)
__global__ __launch_bounds__(256) void k_init(const float* __restrict__ hid,
                                              u16* __restrict__ ring,
                                              unsigned* __restrict__ flags) {
  int i = blockIdx.x * 256 + threadIdx.x;
  ring[i] = f2bf(hid[i]);
  if (blockIdx.x < 16) flags[i] = 0;
}

// ---------------- phase 1: xpart = gather(emb) @ WhxT^T + b_h ----------------
// xpart row m = b*1024 + t.
__global__ __launch_bounds__(256) void k_xpart(const int* __restrict__ xq,
                                               const u16* __restrict__ embB,
                                               const u16* __restrict__ WhxT,
                                               const float* __restrict__ bh,
                                               float* __restrict__ xpart) {
  __shared__ __align__(16) u16 As[128 * 32];
  __shared__ __align__(16) u16 Bs[128 * 32];
  __shared__ int sx[128];
  int bid = blockIdx.x;
  int cpx = gridDim.x >> 3;
  int swz = (bid & 7) * cpx + (bid >> 3);
  int tm = (swz >> 3) * 128, tn = (swz & 7) * 128;
  int tid = threadIdx.x, lane = tid & 63, w = tid >> 6;
  int wm = (w >> 1) * 64, wn = (w & 1) * 64;
  if (tid < 128) sx[tid] = xq[tm + tid];
  __syncthreads();
  int r0 = tid >> 2, sub = tid & 3;
  const u16* ga0 = embB + (size_t)sx[r0] * 512 + sub * 8;
  const u16* ga1 = embB + (size_t)sx[64 + r0] * 512 + sub * 8;
  const u16* gb0 = WhxT + (size_t)(tn + r0) * 512 + sub * 8;
  const u16* gb1 = WhxT + (size_t)(tn + 64 + r0) * 512 + sub * 8;
  f32x4 acc[4][4] = {};
  int rl = lane & 15, kb = (lane >> 4) * 8;
  for (int kt = 0; kt < 16; ++kt) {
    int k0 = kt * 32;
    __syncthreads();
    GLOAD16(ga0 + k0, As + w * 512);
    GLOAD16(ga1 + k0, As + 2048 + w * 512);
    GLOAD16(gb0 + k0, Bs + w * 512);
    GLOAD16(gb1 + k0, Bs + 2048 + w * 512);
    __syncthreads();
    bf16x8 af[4], bf[4];
    #pragma unroll
    for (int mi = 0; mi < 4; mi++) af[mi] = *(const bf16x8*)&As[(wm + mi*16 + rl) * 32 + kb];
    #pragma unroll
    for (int ni = 0; ni < 4; ni++) bf[ni] = *(const bf16x8*)&Bs[(wn + ni*16 + rl) * 32 + kb];
    #pragma unroll
    for (int mi = 0; mi < 4; mi++)
      #pragma unroll
      for (int ni = 0; ni < 4; ni++)
        acc[mi][ni] = mfma16(af[mi], bf[ni], acc[mi][ni]);
  }
  int rq = (lane >> 4) << 2;
  #pragma unroll
  for (int ni = 0; ni < 4; ni++) {
    int col = tn + wn + ni*16 + rl;
    float bias = bh[col];
    #pragma unroll
    for (int mi = 0; mi < 4; mi++) {
      int row = tm + wm + mi*16 + rq;
      #pragma unroll
      for (int r = 0; r < 4; r++)
        xpart[(size_t)(row + r) * 1024 + col] = acc[mi][ni][r] + bias;
    }
  }
}

// ---------------- phase 2: interleaved persistent recurrence ----------------
// 16 blocks x 256 thr (4 waves). Block owns 64 j; W slice (64x1024 bf16 =
// 128KB) in LDS, XOR-swizzled so each ds_read_b128 hits the 8-access/bank
// floor. TWO independent jobs (A = batches 0..15, B = 16..31) interleaved per
// superstep: pollA -> computeA -> postA -> pollB -> computeB -> postB. Each
// job's flag round-trip (~3-4k cy through the coherence point) is hidden
// under the other job's compute. Full M=16 MFMA columns; wave = 16 j, full
// K=1024 in-wave (no cross-wave reduce). Sync protocol identical to r5/r8
// (sc1-atomic h stores, vmcnt(0) drain, barrier, tid0 flag, wave-0 poll).
__global__ __launch_bounds__(256) void k_rnn(const u16* __restrict__ WhhT,
                                             const float* __restrict__ xpart,
                                             u16* __restrict__ ring,
                                             float* __restrict__ hfinal,
                                             unsigned* __restrict__ flags) {
  __shared__ __align__(16) u16 Wlds[64 * 1024];       // 128KB, swizzled
  const int bid = blockIdx.x, tid = threadIdx.x;
  const int lane = tid & 63, wv = tid >> 6;           // 4 waves = 4 j-tiles
  const int rl = lane & 15, kq = lane >> 4;
  const int jbase = bid * 64;
  const int jl = wv * 16 + rl;                        // local j row (A-frag)
  const int xr = (rl & 7) << 3;                       // read swizzle (elems)
  const int j0 = jbase + wv * 16 + kq * 4;            // first of 4 output j

  // stage W slice -> LDS (once): elem (j,k) at [ (j*1024+k) ^ ((j&7)<<3) ]
  for (int e = tid * 8; e < 65536; e += 2048) {
    int j = e >> 10;
    bf16x8 wval = *(const bf16x8*)&WhhT[(size_t)(jbase + j) * 1024 + (e & 1023)];
    *(bf16x8*)&Wlds[e ^ ((j & 7) << 3)] = wval;
  }
  __syncthreads();

  const int arow = jl * 1024 + kq * 8;                // A elem base (pre-XOR)

  for (int t = 0; t < 1024; ++t) {
    #pragma unroll
    for (int jb = 0; jb < 2; ++jb) {
      const int b = jb * 16 + rl;                     // this lane's batch col
      // ---- gate: wait for all 16 blocks' step-t h of this job ----
      if (t > 0) {
        if (wv == 0) {
          const unsigned* fp = flags + (jb * 16 + rl) * 32;  // 4 lanes/flag
          unsigned tgt = (unsigned)t;
          for (;;) {
            unsigned v = __hip_atomic_load(fp, __ATOMIC_RELAXED,
                                           __HIP_MEMORY_SCOPE_AGENT);
            if (!__any((int)(v < tgt))) break;
          }
        }
        __syncthreads();
      }
      // ---- compute: C[j0..j0+3][b] over K=1024 ----
      const u16* hb = ring + (size_t)t * 32768 + (size_t)b * 1024 + kq * 8;
      float4 xp = *(const float4*)&xpart[(size_t)b * 1048576 + (size_t)t * 1024 + j0];
      f32x4 a0 = {0.f,0.f,0.f,0.f}, a1 = a0, a2 = a0, a3 = a0;
      #pragma unroll
      for (int ch = 0; ch < 32; ch += 4) {
        bf16x8 w0 = *(const bf16x8*)&Wlds[(arow + (ch+0)*32) ^ xr];
        bf16x8 w1 = *(const bf16x8*)&Wlds[(arow + (ch+1)*32) ^ xr];
        bf16x8 w2 = *(const bf16x8*)&Wlds[(arow + (ch+2)*32) ^ xr];
        bf16x8 w3 = *(const bf16x8*)&Wlds[(arow + (ch+3)*32) ^ xr];
        bf16x8 h0 = *(const bf16x8*)(hb + (ch+0)*32);
        bf16x8 h1 = *(const bf16x8*)(hb + (ch+1)*32);
        bf16x8 h2 = *(const bf16x8*)(hb + (ch+2)*32);
        bf16x8 h3 = *(const bf16x8*)(hb + (ch+3)*32);
        a0 = mfma16(w0, h0, a0);
        a1 = mfma16(w1, h1, a1);
        a2 = mfma16(w2, h2, a2);
        a3 = mfma16(w3, h3, a3);
      }
      f32x4 s = (a0 + a1) + (a2 + a3);
      float v0 = tanhf(s[0] + xp.x);
      float v1 = tanhf(s[1] + xp.y);
      float v2 = tanhf(s[2] + xp.z);
      float v3 = tanhf(s[3] + xp.w);
      u32 lo = (u32)f2bf(v0) | ((u32)f2bf(v1) << 16);
      u32 hi = (u32)f2bf(v2) | ((u32)f2bf(v3) << 16);
      u64 hv = (u64)lo | ((u64)hi << 32);
      // 4 consecutive j for batch b -> ring slot t+1 (agent scope, to L3/DRAM)
      __hip_atomic_store((u64*)(ring + (size_t)(t + 1) * 32768 + (size_t)b * 1024 + j0),
                         hv, __ATOMIC_RELAXED, __HIP_MEMORY_SCOPE_AGENT);
      if (t == 1023) {
        *(float4*)&hfinal[(size_t)b * 1024 + j0] = make_float4(v0, v1, v2, v3);
      } else {
        // release: drain own stores to the coherence point, order via
        // barrier, then tid0 posts this job's flag.
        asm volatile("s_waitcnt vmcnt(0)" ::: "memory");
        __syncthreads();
        if (tid == 0)
          __hip_atomic_store(flags + (jb * 16 + bid) * 32, (unsigned)(t + 1),
                             __ATOMIC_RELAXED, __HIP_MEMORY_SCOPE_AGENT);
      }
    }
  }
}

// ---------------- phase 3: logits = ringA @ WoT^T + b_o ----------------
// A row m corresponds to (t = m>>5, b = m&31); output row = b*1024 + t.
__global__ __launch_bounds__(256) void k_logits(const u16* __restrict__ A,
                                                const u16* __restrict__ BT,
                                                const float* __restrict__ bo,
                                                float* __restrict__ C) {
  __shared__ __align__(16) u16 As[128 * 32];
  __shared__ __align__(16) u16 Bs[128 * 32];
  int bid = blockIdx.x;
  int cpx = gridDim.x >> 3;
  int swz = (bid & 7) * cpx + (bid >> 3);
  int tm = (swz >> 6) * 128, tn = (swz & 63) * 128;
  int tid = threadIdx.x, lane = tid & 63, w = tid >> 6;
  int wm = (w >> 1) * 64, wn = (w & 1) * 64;
  int r0 = tid >> 2, sub = tid & 3;
  const u16* ga0 = A + (size_t)(tm + r0) * 1024 + sub * 8;
  const u16* ga1 = A + (size_t)(tm + 64 + r0) * 1024 + sub * 8;
  const u16* gb0 = BT + (size_t)(tn + r0) * 1024 + sub * 8;
  const u16* gb1 = BT + (size_t)(tn + 64 + r0) * 1024 + sub * 8;
  f32x4 acc[4][4] = {};
  int rl = lane & 15, kb = (lane >> 4) * 8;
  for (int kt = 0; kt < 32; ++kt) {
    int k0 = kt * 32;
    __syncthreads();
    GLOAD16(ga0 + k0, As + w * 512);
    GLOAD16(ga1 + k0, As + 2048 + w * 512);
    GLOAD16(gb0 + k0, Bs + w * 512);
    GLOAD16(gb1 + k0, Bs + 2048 + w * 512);
    __syncthreads();
    bf16x8 af[4], bf[4];
    #pragma unroll
    for (int mi = 0; mi < 4; mi++) af[mi] = *(const bf16x8*)&As[(wm + mi*16 + rl) * 32 + kb];
    #pragma unroll
    for (int ni = 0; ni < 4; ni++) bf[ni] = *(const bf16x8*)&Bs[(wn + ni*16 + rl) * 32 + kb];
    #pragma unroll
    for (int mi = 0; mi < 4; mi++)
      #pragma unroll
      for (int ni = 0; ni < 4; ni++)
        acc[mi][ni] = mfma16(af[mi], bf[ni], acc[mi][ni]);
  }
  int rq = (lane >> 4) << 2;
  #pragma unroll
  for (int ni = 0; ni < 4; ni++) {
    int col = tn + wn + ni*16 + rl;
    float bias = bo[col];
    #pragma unroll
    for (int mi = 0; mi < 4; mi++) {
      int row = tm + wm + mi*16 + rq;
      #pragma unroll
      for (int r = 0; r < 4; r++) {
        int m = row + r;
        size_t orow = (size_t)(((m & 31) << 10) | (m >> 5));
        C[orow * 8192 + col] = acc[mi][ni][r] + bias;
      }
    }
  }
}

// ---------------- launch ----------------
extern "C" void kernel_launch(void* const* d_in, const int* in_sizes, int n_in,
                              void* d_out, int out_size, void* d_ws, size_t ws_size,
                              hipStream_t stream) {
  const int*   x   = (const int*)  d_in[0];
  const float* hid = (const float*)d_in[1];
  const float* emb = (const float*)d_in[2];
  const float* Wh  = (const float*)d_in[3];
  const float* bh  = (const float*)d_in[4];
  const float* Wo  = (const float*)d_in[5];
  const float* bo  = (const float*)d_in[6];
  float* logits = (float*)d_out;                       // [32768][8192]
  float* hfinal = logits + (size_t)32768 * 8192;       // [32][1024]

  char* ws = (char*)d_ws;
  size_t off = 0;
  auto alloc = [&](size_t bytes) {
    char* p = ws + off;
    off += (bytes + 255) & ~(size_t)255;
    return p;
  };
  u16*   embB  = (u16*)  alloc((size_t)8192 * 512 * 2);    //  8 MB
  u16*   WhxT  = (u16*)  alloc((size_t)1024 * 512 * 2);    //  1 MB
  u16*   WhhT  = (u16*)  alloc((size_t)1024 * 1024 * 2);   //  2 MB
  u16*   WoT   = (u16*)  alloc((size_t)8192 * 1024 * 2);   // 16 MB
  float* xpart = (float*)alloc((size_t)32768 * 1024 * 4);  // 128 MB, row=b*1024+t
  u16*   ring  = (u16*)  alloc((size_t)1025 * 32768 * 2);  // 67.1 MB (slot t = h_t)
  unsigned* flags = (unsigned*)alloc(16384);               // 32 flags, 128B apart
  (void)ws_size; (void)in_sizes; (void)n_in; (void)out_size;

  k_cvt_emb<<<4096, 256, 0, stream>>>(emb, embB);
  k_tr_wh  <<<1536, 256, 0, stream>>>(Wh, WhxT, WhhT);
  k_tr_wo  <<<8192, 256, 0, stream>>>(Wo, WoT);
  k_init   <<<128,  256, 0, stream>>>(hid, ring, flags);
  k_xpart  <<<2048, 256, 0, stream>>>(x, embB, WhxT, bh, xpart);
  k_rnn    <<<16,   256, 0, stream>>>(WhhT, xpart, ring, hfinal, flags);
  k_logits <<<16384,256, 0, stream>>>(ring + 32768, WoT, bo, logits);
}

// Round 10
// 5004.482 us; speedup vs baseline: 2.2597x; 2.2597x over previous
//
#include <hip/hip_runtime.h>
#include <hip/hip_bf16.h>

typedef unsigned short u16;
typedef unsigned int   u32;
typedef unsigned long long u64;
typedef __attribute__((ext_vector_type(8))) __bf16 bf16x8;
typedef __attribute__((ext_vector_type(4))) float   f32x4;

// async global->LDS, 16B per lane; LDS dest = wave-uniform base + lane*16
#define GLOAD16(gp, lp) __builtin_amdgcn_global_load_lds( \
    (__attribute__((address_space(1))) void*)(gp),        \
    (__attribute__((address_space(3))) void*)(lp), 16, 0, 0)

static __device__ __forceinline__ u16 f2bf(float f) {
  __bf16 b = (__bf16)f;                 // RNE convert
  return __builtin_bit_cast(u16, b);
}
static __device__ __forceinline__ f32x4 mfma16(bf16x8 a, bf16x8 b, f32x4 c) {
  return __builtin_amdgcn_mfma_f32_16x16x32_bf16(a, b, c, 0, 0, 0);
}
// coherent (agent-scope, relaxed) 16B load as 2x8B atomics: bypasses L1/L2,
// served at the coherence point; NO cache-maintenance instructions emitted.
static __device__ __forceinline__ bf16x8 ald16(const u16* p) {
  union { u64 q[2]; bf16x8 v; } u;
  u.q[0] = __hip_atomic_load((const u64*)p,       __ATOMIC_RELAXED, __HIP_MEMORY_SCOPE_AGENT);
  u.q[1] = __hip_atomic_load((const u64*)(p + 4), __ATOMIC_RELAXED, __HIP_MEMORY_SCOPE_AGENT);
  return u.v;
}

// ---------------- prep kernels ----------------

__global__ __launch_bounds__(256) void k_cvt_emb(const float* __restrict__ s,
                                                 u16* __restrict__ d) {
  int i = (blockIdx.x * 256 + threadIdx.x) * 4;
  float4 v = *(const float4*)(s + i);
  d[i] = f2bf(v.x); d[i+1] = f2bf(v.y); d[i+2] = f2bf(v.z); d[i+3] = f2bf(v.w);
}

__global__ __launch_bounds__(256) void k_tr_wh(const float* __restrict__ Wh,
                                               u16* __restrict__ WhxT,
                                               u16* __restrict__ WhhT) {
  __shared__ float tile[32][33];
  int bx = blockIdx.x & 31;
  int be = blockIdx.x >> 5;
  int tx = threadIdx.x & 31, ty = threadIdx.x >> 5;
  #pragma unroll
  for (int s = 0; s < 32; s += 8)
    tile[ty + s][tx] = Wh[(size_t)(be*32 + ty + s) * 1024 + bx*32 + tx];
  __syncthreads();
  #pragma unroll
  for (int s = 0; s < 32; s += 8) {
    int e = be*32 + tx;
    int j = bx*32 + ty + s;
    u16 v = f2bf(tile[tx][ty + s]);
    if (e < 512) WhxT[(size_t)j * 512 + e] = v;
    else         WhhT[(size_t)j * 1024 + (e - 512)] = v;
  }
}

__global__ __launch_bounds__(256) void k_tr_wo(const float* __restrict__ Wo,
                                               u16* __restrict__ WoT) {
  __shared__ float tile[32][33];
  int bx = blockIdx.x & 255;
  int by = blockIdx.x >> 8;
  int tx = threadIdx.x & 31, ty = threadIdx.x >> 5;
  #pragma unroll
  for (int s = 0; s < 32; s += 8)
    tile[ty + s][tx] = Wo[(size_t)(by*32 + ty + s) * 8192 + bx*32 + tx];
  __syncthreads();
  #pragma unroll
  for (int s = 0; s < 32; s += 8)
    WoT[(size_t)(bx*32 + ty + s) * 1024 + by*32 + tx] = f2bf(tile[tx][ty + s]);
}

// h0 -> ring slot 0; zero flags
__global__ __launch_bounds__(256) void k_init(const float* __restrict__ hid,
                                              u16* __restrict__ ring,
                                              unsigned* __restrict__ flags) {
  int i = blockIdx.x * 256 + threadIdx.x;
  ring[i] = f2bf(hid[i]);
  if (blockIdx.x < 8) flags[i] = 0;      // zero the full padded 8 KB flag region
}

// ---------------- phase 1: xpart = gather(emb) @ WhxT^T + b_h ----------------
__global__ __launch_bounds__(256) void k_xpart(const int* __restrict__ xq,
                                               const u16* __restrict__ embB,
                                               const u16* __restrict__ WhxT,
                                               const float* __restrict__ bh,
                                               float* __restrict__ xpart) {
  __shared__ __align__(16) u16 As[128 * 32];
  __shared__ __align__(16) u16 Bs[128 * 32];
  __shared__ int sx[128];
  int bid = blockIdx.x;
  int cpx = gridDim.x >> 3;
  int swz = (bid & 7) * cpx + (bid >> 3);
  int tm = (swz >> 3) * 128, tn = (swz & 7) * 128;
  int tid = threadIdx.x, lane = tid & 63, w = tid >> 6;
  int wm = (w >> 1) * 64, wn = (w & 1) * 64;
  if (tid < 128) sx[tid] = xq[tm + tid];
  __syncthreads();
  int r0 = tid >> 2, sub = tid & 3;
  const u16* ga0 = embB + (size_t)sx[r0] * 512 + sub * 8;
  const u16* ga1 = embB + (size_t)sx[64 + r0] * 512 + sub * 8;
  const u16* gb0 = WhxT + (size_t)(tn + r0) * 512 + sub * 8;
  const u16* gb1 = WhxT + (size_t)(tn + 64 + r0) * 512 + sub * 8;
  f32x4 acc[4][4] = {};
  int rl = lane & 15, kb = (lane >> 4) * 8;
  for (int kt = 0; kt < 16; ++kt) {
    int k0 = kt * 32;
    __syncthreads();
    GLOAD16(ga0 + k0, As + w * 512);
    GLOAD16(ga1 + k0, As + 2048 + w * 512);
    GLOAD16(gb0 + k0, Bs + w * 512);
    GLOAD16(gb1 + k0, Bs + 2048 + w * 512);
    __syncthreads();
    bf16x8 af[4], bf[4];
    #pragma unroll
    for (int mi = 0; mi < 4; mi++) af[mi] = *(const bf16x8*)&As[(wm + mi*16 + rl) * 32 + kb];
    #pragma unroll
    for (int ni = 0; ni < 4; ni++) bf[ni] = *(const bf16x8*)&Bs[(wn + ni*16 + rl) * 32 + kb];
    #pragma unroll
    for (int mi = 0; mi < 4; mi++)
      #pragma unroll
      for (int ni = 0; ni < 4; ni++)
        acc[mi][ni] = mfma16(af[mi], bf[ni], acc[mi][ni]);
  }
  int rq = (lane >> 4) << 2;
  #pragma unroll
  for (int ni = 0; ni < 4; ni++) {
    int col = tn + wn + ni*16 + rl;
    float bias = bh[col];
    #pragma unroll
    for (int mi = 0; mi < 4; mi++) {
      int row = tm + wm + mi*16 + rq;
      #pragma unroll
      for (int r = 0; r < 4; r++)
        xpart[(size_t)(row + r) * 1024 + col] = acc[mi][ni][r] + bias;
    }
  }
}

// ---------------- phase 2: persistent recurrence (r5 structure, verbatim) ----
// 64 blocks x 256 threads; block owns 16 H-columns; W in VGPRs (no LDS tile).
// h exchanged through a ring buffer; producers store 8B agent-scope; consumers
// plain cached loads at fresh addresses (r5-proven). Added vs r5: a FINAL flag
// post (value 1024) after the last ring store, so gated consumers (k_logits)
// can release on the tail timesteps.
__global__ __launch_bounds__(256) void k_rnn(const u16* __restrict__ WhhT,
                                             const float* __restrict__ xpart,
                                             u16* __restrict__ ring,
                                             float* __restrict__ hfinal,
                                             unsigned* __restrict__ flags) {
  __shared__ __align__(16) float psh[2048];       // partials [w*2+mi][lane][4]
  int bid = blockIdx.x, tid = threadIdx.x, lane = tid & 63, w = tid >> 6;
  int jbase = bid * 16;
  const int rl = lane & 15;
  const int kbase = w * 256 + ((lane >> 4) << 3);
  // W fragments resident in VGPRs for the whole kernel (32 VGPRs)
  bf16x8 Wreg[8];
  #pragma unroll
  for (int ki = 0; ki < 8; ++ki)
    Wreg[ki] = *(const bf16x8*)&WhhT[(size_t)(jbase + rl) * 1024 + kbase + ki * 32];
  // reduce thread rid in [0,128): owns (b = rid>>2, 4 consecutive j at jq)
  const bool red = (tid < 128);
  int b = 0, jq = 0, mi = 0, lsrc = 0, rg = 0;
  float4 xpre = make_float4(0.f, 0.f, 0.f, 0.f);
  if (red) {
    b = tid >> 2; jq = (tid & 3) << 2;
    mi = b >> 4;
    int bb = b & 15;
    lsrc = (bb >> 2) << 4;          // source lane base: + j gives lane
    rg = bb & 3;                    // source reg (C/D row-within-4)
    xpre = *(const float4*)&xpart[(size_t)(b * 1024 + 0) * 1024 + jbase + jq];
  }
  for (int t = 0; t < 1024; ++t) {
    const u16* hprev = ring + (size_t)t * 32768;        // slot t, fresh lines
    // plain cached loads; pipeline under one L2/L3 latency
    bf16x8 ha[16];
    #pragma unroll
    for (int ki = 0; ki < 8; ++ki) {
      int k = kbase + ki * 32;
      ha[ki*2 + 0] = *(const bf16x8*)&hprev[(size_t)rl * 1024 + k];
      ha[ki*2 + 1] = *(const bf16x8*)&hprev[(size_t)(16 + rl) * 1024 + k];
    }
    f32x4 acc0 = {0.f, 0.f, 0.f, 0.f}, acc1 = {0.f, 0.f, 0.f, 0.f};
    #pragma unroll
    for (int ki = 0; ki < 8; ++ki) {
      acc0 = mfma16(ha[ki*2 + 0], Wreg[ki], acc0);
      acc1 = mfma16(ha[ki*2 + 1], Wreg[ki], acc1);
    }
    *(f32x4*)&psh[((w * 2 + 0) * 64 + lane) * 4] = acc0;
    *(f32x4*)&psh[((w * 2 + 1) * 64 + lane) * 4] = acc1;
    __syncthreads();
    if (red) {
      float s0 = 0.f, s1 = 0.f, s2 = 0.f, s3 = 0.f;
      #pragma unroll
      for (int ww = 0; ww < 4; ++ww) {
        const float* pp = &psh[((ww * 2 + mi) * 64) * 4];
        s0 += pp[(lsrc + jq + 0) * 4 + rg];
        s1 += pp[(lsrc + jq + 1) * 4 + rg];
        s2 += pp[(lsrc + jq + 2) * 4 + rg];
        s3 += pp[(lsrc + jq + 3) * 4 + rg];
      }
      float v0 = tanhf(s0 + xpre.x);
      float v1 = tanhf(s1 + xpre.y);
      float v2 = tanhf(s2 + xpre.z);
      float v3 = tanhf(s3 + xpre.w);
      u32 lo = (u32)f2bf(v0) | ((u32)f2bf(v1) << 16);
      u32 hi = (u32)f2bf(v2) | ((u32)f2bf(v3) << 16);
      u64 hv = (u64)lo | ((u64)hi << 32);
      // single h store: ring slot t+1 (this IS the hall data for phase 3)
      __hip_atomic_store((u64*)(ring + (size_t)(t + 1) * 32768 + b * 1024 + jbase + jq),
                         hv, __ATOMIC_RELAXED, __HIP_MEMORY_SCOPE_AGENT);
      if (t == 1023)
        *(float4*)&hfinal[b * 1024 + jbase + jq] = make_float4(v0, v1, v2, v3);
    }
    if (t < 1023) {
      // release: drain own stores to the coherence point, order via barrier,
      // then tid0 posts the flag. No cache-maintenance instructions.
      asm volatile("s_waitcnt vmcnt(0)" ::: "memory");
      __syncthreads();
      if (tid == 0)
        __hip_atomic_store(&flags[bid * 32], (unsigned)(t + 1),
                           __ATOMIC_RELAXED, __HIP_MEMORY_SCOPE_AGENT);
      if (red)                                      // prefetch under the spin
        xpre = *(const float4*)&xpart[((size_t)(b * 1024 + (t + 1))) * 1024 + jbase + jq];
      if (w == 0) {                                 // lane i watches flags[i*32]
        while (__hip_atomic_load(&flags[lane * 32], __ATOMIC_RELAXED,
                                 __HIP_MEMORY_SCOPE_AGENT) < (unsigned)(t + 1)) { }
      }
      __syncthreads();
    } else {
      // final publish for gated logits consumers: slot 1024 drained -> flag 1024
      asm volatile("s_waitcnt vmcnt(0)" ::: "memory");
      __syncthreads();
      if (tid == 0)
        __hip_atomic_store(&flags[bid * 32], 1024u,
                           __ATOMIC_RELAXED, __HIP_MEMORY_SCOPE_AGENT);
    }
  }
}

// ---------------- phase 3: gated logits = ringA @ WoT^T + b_o ----------------
// Runs CONCURRENTLY with k_rnn on the idle CUs. A row m = ring slot (m>>5)+1,
// batch m&31; a 128-row tile touches t in [tIdx*4, tIdx*4+4) only, so the
// block gates on all 64 flags >= tIdx*4+4 (sleep-poll, light on flag lines).
// Blocks ordered so tIdx ascends with blockIdx (release in dispatch order).
// No deadlock: k_rnn never waits on us; gates are eventually satisfied.
__global__ __launch_bounds__(256) void k_logits(const u16* __restrict__ A,
                                                const u16* __restrict__ BT,
                                                const float* __restrict__ bo,
                                                float* __restrict__ C,
                                                const unsigned* __restrict__ flags) {
  __shared__ __align__(16) u16 As[128 * 32];
  __shared__ __align__(16) u16 Bs[128 * 32];
  int bid = blockIdx.x;
  int tIdx = bid >> 6, vIdx = bid & 63;          // t ascends with blockIdx
  int tm = tIdx * 128, tn = vIdx * 128;
  int tid = threadIdx.x, lane = tid & 63, w = tid >> 6;
  // ---- gate: wait until ring slots [tIdx*4+1 .. tIdx*4+4] are published ----
  if (tid < 64) {
    unsigned tgt = (unsigned)(tIdx * 4 + 4);     // == 1024 for the last tiles
    const unsigned* fp = flags + tid * 32;
    for (;;) {
      unsigned v = __hip_atomic_load(fp, __ATOMIC_RELAXED, __HIP_MEMORY_SCOPE_AGENT);
      if (!__any((int)(v < tgt))) break;
      __builtin_amdgcn_s_sleep(32);
    }
  }
  __syncthreads();
  int wm = (w >> 1) * 64, wn = (w & 1) * 64;
  int r0 = tid >> 2, sub = tid & 3;
  const u16* ga0 = A + (size_t)(tm + r0) * 1024 + sub * 8;
  const u16* ga1 = A + (size_t)(tm + 64 + r0) * 1024 + sub * 8;
  const u16* gb0 = BT + (size_t)(tn + r0) * 1024 + sub * 8;
  const u16* gb1 = BT + (size_t)(tn + 64 + r0) * 1024 + sub * 8;
  f32x4 acc[4][4] = {};
  int rl = lane & 15, kb = (lane >> 4) * 8;
  for (int kt = 0; kt < 32; ++kt) {
    int k0 = kt * 32;
    __syncthreads();
    GLOAD16(ga0 + k0, As + w * 512);
    GLOAD16(ga1 + k0, As + 2048 + w * 512);
    GLOAD16(gb0 + k0, Bs + w * 512);
    GLOAD16(gb1 + k0, Bs + 2048 + w * 512);
    __syncthreads();
    bf16x8 af[4], bf[4];
    #pragma unroll
    for (int mi = 0; mi < 4; mi++) af[mi] = *(const bf16x8*)&As[(wm + mi*16 + rl) * 32 + kb];
    #pragma unroll
    for (int ni = 0; ni < 4; ni++) bf[ni] = *(const bf16x8*)&Bs[(wn + ni*16 + rl) * 32 + kb];
    #pragma unroll
    for (int mi = 0; mi < 4; mi++)
      #pragma unroll
      for (int ni = 0; ni < 4; ni++)
        acc[mi][ni] = mfma16(af[mi], bf[ni], acc[mi][ni]);
  }
  int rq = (lane >> 4) << 2;
  #pragma unroll
  for (int ni = 0; ni < 4; ni++) {
    int col = tn + wn + ni*16 + rl;
    float bias = bo[col];
    #pragma unroll
    for (int mi = 0; mi < 4; mi++) {
      int row = tm + wm + mi*16 + rq;
      #pragma unroll
      for (int r = 0; r < 4; r++) {
        int m = row + r;
        size_t orow = (size_t)(((m & 31) << 10) | (m >> 5));
        C[orow * 8192 + col] = acc[mi][ni][r] + bias;
      }
    }
  }
}

// ---------------- launch ----------------
extern "C" void kernel_launch(void* const* d_in, const int* in_sizes, int n_in,
                              void* d_out, int out_size, void* d_ws, size_t ws_size,
                              hipStream_t stream) {
  const int*   x   = (const int*)  d_in[0];
  const float* hid = (const float*)d_in[1];
  const float* emb = (const float*)d_in[2];
  const float* Wh  = (const float*)d_in[3];
  const float* bh  = (const float*)d_in[4];
  const float* Wo  = (const float*)d_in[5];
  const float* bo  = (const float*)d_in[6];
  float* logits = (float*)d_out;                       // [32768][8192]
  float* hfinal = logits + (size_t)32768 * 8192;       // [32][1024]

  char* ws = (char*)d_ws;
  size_t off = 0;
  auto alloc = [&](size_t bytes) {
    char* p = ws + off;
    off += (bytes + 255) & ~(size_t)255;
    return p;
  };
  u16*   embB  = (u16*)  alloc((size_t)8192 * 512 * 2);    //  8 MB
  u16*   WhxT  = (u16*)  alloc((size_t)1024 * 512 * 2);    //  1 MB
  u16*   WhhT  = (u16*)  alloc((size_t)1024 * 1024 * 2);   //  2 MB
  u16*   WoT   = (u16*)  alloc((size_t)8192 * 1024 * 2);   // 16 MB
  float* xpart = (float*)alloc((size_t)32768 * 1024 * 4);  // 128 MB, row=b*1024+t
  u16*   ring  = (u16*)  alloc((size_t)1025 * 32768 * 2);  // 67.1 MB (slot t = h_t)
  unsigned* flags = (unsigned*)alloc(8192);                // 64 flags, 128B apart
  (void)ws_size; (void)in_sizes; (void)n_in; (void)out_size;

  k_cvt_emb<<<4096, 256, 0, stream>>>(emb, embB);
  k_tr_wh  <<<1536, 256, 0, stream>>>(Wh, WhxT, WhhT);
  k_tr_wo  <<<8192, 256, 0, stream>>>(Wo, WoT);
  k_init   <<<128,  256, 0, stream>>>(hid, ring, flags);
  k_xpart  <<<2048, 256, 0, stream>>>(x, embB, WhxT, bh, xpart);
  k_rnn    <<<64,   256, 0, stream>>>(WhhT, xpart, ring, hfinal, flags);
  k_logits <<<16384,256, 0, stream>>>(ring + 32768, WoT, bo, logits, flags);
}